// Round 11
// baseline (496.187 us; speedup 1.0000x reference)
//
#include <hip/hip_runtime.h>
#include <math.h>

#define HD 128
#define PB 512   // partition blocks for bucketed CSR build (2 blocks/CU)
#define SCB 4096 // elements per block in multi-block scan
#define MT 8     // row-tiles per GEMM block (weights-resident loop)

typedef __attribute__((ext_vector_type(8))) short short8;
typedef __attribute__((ext_vector_type(4))) float f32x4;
typedef __attribute__((ext_vector_type(2))) float f32x2;
typedef __attribute__((ext_vector_type(4))) unsigned u32x4;

__device__ __forceinline__ float sigf(float v) { return 1.0f / (1.0f + __expf(-v)); }
// tanh(x) = 1 - 2/(e^{2x}+1); exact to ~1e-7 rel, saturates correctly. Avoids libm tanhf.
__device__ __forceinline__ float tanhf_fast(float v) {
  float e = __expf(2.0f * v);
  return 1.0f - 2.0f / (e + 1.0f);
}

__device__ __forceinline__ unsigned short f2bf(float f) {
  union { float f; unsigned u; } v; v.f = f;
  unsigned r = (v.u + 0x7fffu + ((v.u >> 16) & 1u)) >> 16;
  return (unsigned short)r;
}
__device__ __forceinline__ float bf2f(unsigned short b) {
  union { unsigned u; float f; } v; v.u = ((unsigned)b) << 16;
  return v.f;
}

// ---------------- CSR build ----------------

__global__ __launch_bounds__(256) void bcount_k(const int* __restrict__ ei,
                                                int* __restrict__ bcnt,
                                                int E, int N, int shift, int NB) {
  __shared__ int h[256];
  const int blk = blockIdx.x, tid = threadIdx.x;
  h[tid] = 0;
  __syncthreads();
  int per = (E + PB - 1) / PB;
  int lo = blk * per;
  int hi = (lo + per < E) ? lo + per : E;
  for (int e = lo + tid; e < hi; e += 256) {
    int d = ei[(size_t)E + e];
    if ((unsigned)d >= (unsigned)N) continue;
    atomicAdd(&h[d >> shift], 1);
  }
  __syncthreads();
  if (tid < NB) bcnt[tid * PB + blk] = h[tid];
}

__global__ __launch_bounds__(256) void scan1_k(const int* __restrict__ a,
                                               int* __restrict__ bsums, int total) {
  __shared__ int ts[256];
  int b = blockIdx.x, tid = threadIdx.x;
  int lo = b * SCB + tid * 16;
  int s = 0;
#pragma unroll
  for (int i = 0; i < 16; ++i) {
    int idx = lo + i;
    if (idx < total) s += a[idx];
  }
  ts[tid] = s;
  __syncthreads();
  for (int off = 128; off > 0; off >>= 1) {
    if (tid < off) ts[tid] += ts[tid + off];
    __syncthreads();
  }
  if (tid == 0) bsums[b] = ts[0];
}

__global__ __launch_bounds__(256) void scan2_k(int* __restrict__ bsums, int nb) {
  __shared__ int ts[256];
  int tid = threadIdx.x;
  int v = (tid < nb) ? bsums[tid] : 0;
  ts[tid] = v;
  __syncthreads();
  for (int off = 1; off < 256; off <<= 1) {
    int u = (tid >= off) ? ts[tid - off] : 0;
    __syncthreads();
    ts[tid] += u;
    __syncthreads();
  }
  if (tid < nb) bsums[tid] = ts[tid] - v;  // exclusive
}

__global__ __launch_bounds__(256) void scan3_k(int* __restrict__ a,
                                               const int* __restrict__ bsums,
                                               int total, int nblk) {
  __shared__ int ts[256];
  int b = blockIdx.x, tid = threadIdx.x;
  int lo = b * SCB + tid * 16;
  int pre[16];
  int s = 0;
#pragma unroll
  for (int i = 0; i < 16; ++i) {
    int idx = lo + i;
    int xv = (idx < total) ? a[idx] : 0;
    pre[i] = s;
    s += xv;
  }
  ts[tid] = s;
  __syncthreads();
  for (int off = 1; off < 256; off <<= 1) {
    int u = (tid >= off) ? ts[tid - off] : 0;
    __syncthreads();
    ts[tid] += u;
    __syncthreads();
  }
  int off0 = ts[tid] - s + bsums[b];
#pragma unroll
  for (int i = 0; i < 16; ++i) {
    int idx = lo + i;
    if (idx < total) a[idx] = off0 + pre[i];
  }
  if (b == nblk - 1 && tid == 255) a[total] = off0 + s;  // grand total
}

__global__ __launch_bounds__(256) void bpart_k(const int* __restrict__ ei,
                                               const int* __restrict__ bstart,
                                               unsigned* __restrict__ ebuf,
                                               int E, int N, int shift, int NB,
                                               int sbits) {
  __shared__ int cur[256];
  const int blk = blockIdx.x, tid = threadIdx.x;
  if (tid < NB) cur[tid] = bstart[tid * PB + blk];
  __syncthreads();
  int per = (E + PB - 1) / PB;
  int lo = blk * per;
  int hi = (lo + per < E) ? lo + per : E;
  const unsigned dmask = (1u << shift) - 1u;
  for (int e = lo + tid; e < hi; e += 256) {
    int s = ei[e];
    int d = ei[(size_t)E + e];
    if ((unsigned)s >= (unsigned)N || (unsigned)d >= (unsigned)N) continue;
    int p = atomicAdd(&cur[d >> shift], 1);
    ebuf[p] = (((unsigned)d & dmask) << sbits) | (unsigned)s;
  }
}

__global__ __launch_bounds__(256) void bfill2_k(const unsigned* __restrict__ ebuf,
                                                const int* __restrict__ bstart,
                                                int* __restrict__ rowstart,
                                                int* __restrict__ csr,
                                                int N, int shift, int NB, int sbits) {
  __shared__ int cnt[2048];
  __shared__ int tsum[256];
  const int b = blockIdx.x, tid = threadIdx.x;
  const int d0 = b << shift;
  int dmax = d0 + (1 << shift);
  if (dmax > N) dmax = N;
  const int nd = dmax - d0;
  const unsigned smask = (1u << sbits) - 1u;
  for (int i = tid; i < nd; i += 256) cnt[i] = 0;
  __syncthreads();
  const int base = bstart[b * PB];
  const int end = bstart[(b + 1) * PB];  // b=NB-1 -> bstart[NB*PB] = grand total
  for (int idx = base + tid; idx < end; idx += 256)
    atomicAdd(&cnt[ebuf[idx] >> sbits], 1);
  __syncthreads();
  const int C = (nd + 255) / 256;  // <= 8
  int lo = tid * C;
  int hi = (lo + C < nd) ? lo + C : nd;
  int loc[8];
  int s = 0;
  for (int i = lo; i < hi; ++i) {
    loc[i - lo] = cnt[i];
    s += cnt[i];
  }
  tsum[tid] = s;
  __syncthreads();
  for (int off = 1; off < 256; off <<= 1) {
    int u = (tid >= off) ? tsum[tid - off] : 0;
    __syncthreads();
    tsum[tid] += u;
    __syncthreads();
  }
  int run = tsum[tid] - s + base;
  for (int i = lo; i < hi; ++i) {
    rowstart[d0 + i] = run;
    cnt[i] = run;  // becomes the cursor
    run += loc[i - lo];
  }
  if (b == NB - 1 && tid == 255) rowstart[N] = end;
  __syncthreads();
  for (int idx = base + tid; idx < end; idx += 256) {
    unsigned pk = ebuf[idx];
    int p = atomicAdd(&cnt[pk >> sbits], 1);
    csr[p] = (int)(pk & smask);
  }
}

// ---------------- conversions (separate kernels) ----------------

__global__ __launch_bounds__(256) void convx_k(const float* __restrict__ x,
                                               unsigned short* __restrict__ xb,
                                               unsigned* __restrict__ x8, int n4) {
  int t = blockIdx.x * 256 + threadIdx.x;
  if (t >= n4) return;
  float4 v = reinterpret_cast<const float4*>(x)[t];
  ushort4 o;
  o.x = f2bf(v.x); o.y = f2bf(v.y); o.z = f2bf(v.z); o.w = f2bf(v.w);
  reinterpret_cast<ushort4*>(xb)[t] = o;
  int p8 = 0;
  p8 = __builtin_amdgcn_cvt_pk_fp8_f32(v.x, v.y, p8, false);  // bytes 0,1
  p8 = __builtin_amdgcn_cvt_pk_fp8_f32(v.z, v.w, p8, true);   // bytes 2,3
  x8[t] = (unsigned)p8;
}

__global__ __launch_bounds__(256) void prepw_k(
    const float* __restrict__ gwhh, const float* __restrict__ lwih,
    const float* __restrict__ lbih, const float* __restrict__ lbhh,
    unsigned short* __restrict__ gwhhb, unsigned short* __restrict__ lwb,
    float* __restrict__ lbias) {
  int t = blockIdx.x * 256 + threadIdx.x;
  if (t < 49152) { gwhhb[t] = f2bf(gwhh[t]); return; }
  t -= 49152;
  if (t < 49152) {  // select i,g,o rows of [512,128]
    int j = t >> 7, k = t & 127;
    int jm = j < 128 ? j : j + 128;
    lwb[t] = f2bf(lwih[(size_t)jm * 128 + k]);
    return;
  }
  t -= 49152;
  if (t < 384) {
    int jm = t < 128 ? t : t + 128;
    lbias[t] = lbih[jm] + lbhh[jm];
  }
}

// Bp[j,k] = sum_c W[k,c] * gwih[j,c]  (fold of conv-W into GRU input weight)
__global__ __launch_bounds__(256) void prepbp_k(const float* __restrict__ W,
                                                const float* __restrict__ gwih,
                                                unsigned short* __restrict__ Bpb) {
  int t = blockIdx.x * 256 + threadIdx.x;
  if (t >= 49152) return;
  int j = t >> 7, k = t & 127;
  const float4* wr = reinterpret_cast<const float4*>(W + (size_t)k * 128);
  const float4* gr = reinterpret_cast<const float4*>(gwih + (size_t)j * 128);
  float acc = 0.f;
#pragma unroll
  for (int c = 0; c < 32; ++c) {
    float4 a = wr[c], b = gr[c];
    acc += a.x * b.x + a.y * b.y + a.z * b.z + a.w * b.w;
  }
  Bpb[t] = f2bf(acc);
}

// ---------------- gather (fp8 in, bf16 out) — r1 structure, row-range split ----------------
// Bound by random-transaction rate (~40G/s): 1 transaction/edge is the floor.
__device__ __forceinline__ void accf8(f32x2* acc, uint4 v) {
  acc[0] += __builtin_amdgcn_cvt_pk_f32_fp8((int)v.x, false);
  acc[1] += __builtin_amdgcn_cvt_pk_f32_fp8((int)v.x, true);
  acc[2] += __builtin_amdgcn_cvt_pk_f32_fp8((int)v.y, false);
  acc[3] += __builtin_amdgcn_cvt_pk_f32_fp8((int)v.y, true);
  acc[4] += __builtin_amdgcn_cvt_pk_f32_fp8((int)v.z, false);
  acc[5] += __builtin_amdgcn_cvt_pk_f32_fp8((int)v.z, true);
  acc[6] += __builtin_amdgcn_cvt_pk_f32_fp8((int)v.w, false);
  acc[7] += __builtin_amdgcn_cvt_pk_f32_fp8((int)v.w, true);
}

__global__ __launch_bounds__(256) void gather_f8_k(const int* __restrict__ csr,
                                                   const int* __restrict__ rowstart,
                                                   const unsigned* __restrict__ x8,
                                                   unsigned short* __restrict__ xaggb,
                                                   int row0, int rowend) {
  int w = row0 + (int)(((long long)blockIdx.x * 256 + threadIdx.x) >> 6);
  if (w >= rowend) return;
  const int lane = threadIdx.x & 63;
  const int sub = lane >> 3, li = lane & 7;
  const int beg = rowstart[w], end = rowstart[w + 1];
  const uint4* x4 = reinterpret_cast<const uint4*>(x8);  // row = 8 uint4 (128B)

  f32x2 acc[8];
#pragma unroll
  for (int i = 0; i < 8; ++i) acc[i] = (f32x2)0.f;

  int j = beg;
  for (; j + 16 <= end; j += 16) {
    int s0 = __builtin_nontemporal_load(&csr[j + sub]);
    int s1 = __builtin_nontemporal_load(&csr[j + 8 + sub]);
    uint4 v0 = x4[(size_t)s0 * 8 + li];
    uint4 v1 = x4[(size_t)s1 * 8 + li];
    accf8(acc, v0);
    accf8(acc, v1);
  }
  for (; j + 8 <= end; j += 8) {
    int s0 = __builtin_nontemporal_load(&csr[j + sub]);
    uint4 v0 = x4[(size_t)s0 * 8 + li];
    accf8(acc, v0);
  }
  int rem = end - j;  // 0..7
  if (sub < rem) {
    int s0 = csr[j + sub];
    uint4 v0 = x4[(size_t)s0 * 8 + li];
    accf8(acc, v0);
  }

  float a16[16];
#pragma unroll
  for (int i = 0; i < 8; ++i) { a16[2 * i] = acc[i].x; a16[2 * i + 1] = acc[i].y; }
#pragma unroll
  for (int i = 0; i < 16; ++i) {
    a16[i] += __shfl_xor(a16[i], 8, 64);
    a16[i] += __shfl_xor(a16[i], 16, 64);
    a16[i] += __shfl_xor(a16[i], 32, 64);
  }

  if (lane < 8) {
    float scale = 1.0f / fmaxf((float)(end - beg), 1.0f);
    u32x4 o1, o2;
    o1.x = (unsigned)f2bf(a16[0] * scale) | ((unsigned)f2bf(a16[1] * scale) << 16);
    o1.y = (unsigned)f2bf(a16[2] * scale) | ((unsigned)f2bf(a16[3] * scale) << 16);
    o1.z = (unsigned)f2bf(a16[4] * scale) | ((unsigned)f2bf(a16[5] * scale) << 16);
    o1.w = (unsigned)f2bf(a16[6] * scale) | ((unsigned)f2bf(a16[7] * scale) << 16);
    o2.x = (unsigned)f2bf(a16[8] * scale) | ((unsigned)f2bf(a16[9] * scale) << 16);
    o2.y = (unsigned)f2bf(a16[10] * scale) | ((unsigned)f2bf(a16[11] * scale) << 16);
    o2.z = (unsigned)f2bf(a16[12] * scale) | ((unsigned)f2bf(a16[13] * scale) << 16);
    o2.w = (unsigned)f2bf(a16[14] * scale) | ((unsigned)f2bf(a16[15] * scale) << 16);
    u32x4* dst = reinterpret_cast<u32x4*>(xaggb + (size_t)w * HD) + li * 2;
    dst[0] = o1;   // cached stores: downstream gru reads can hit cache
    dst[1] = o2;
  }
}

// ---------------- fused GRU: weights-resident, MT row-tiles per block ----------------
// Stage BOTH weight sets once (52KB LDS), then loop MT row-tiles with ZERO
// barriers in the loop (A prefetched into regs one tile ahead). Amortizes
// staging+barriers 8x; drops block count 6252 -> ~800 (r10 showed traffic is
// fine; time was per-block structural overhead). XCD swizzle keeps the 4
// col-blocks of a tile-group on one XCD (r10: FETCH 119->26MB).
__global__ __launch_bounds__(256) void gru_fused_k(
    const unsigned short* __restrict__ xaggb, const unsigned short* __restrict__ xb,
    const unsigned short* __restrict__ Bpb, const unsigned short* __restrict__ gwhhb,
    const float* __restrict__ gbih, const float* __restrict__ gbhh,
    unsigned short* __restrict__ hconv, int nrows, int nt, int ngroups) {
  __shared__ unsigned short Bsm[6][32][136];
  const int id = blockIdx.x;
  const int rest = id >> 3;
  const int cg = rest & 3;
  const int g = ((rest >> 2) << 3) | (id & 7);
  if (g >= ngroups) return;  // uniform over block (before any barrier)
  const int tid = threadIdx.x;
  const int w = tid >> 6, lane = tid & 63;
  const int q = lane >> 4, r = lane & 15;
  const int c0 = cg * 32;

  // stage both weight sets: 6 planes x 32 cols (12 x 256 uint4)
#pragma unroll
  for (int it = 0; it < 12; ++it) {
    int idx = it * 256 + tid;
    int p = idx >> 9;
    int rem = idx & 511;
    int col = rem >> 4, kq = rem & 15;
    const unsigned short* src =
        (p < 3) ? Bpb + ((size_t)(p * 128 + c0 + col)) * HD
                : gwhhb + ((size_t)((p - 3) * 128 + c0 + col)) * HD;
    uint4 v = *reinterpret_cast<const uint4*>(src + kq * 8);
    *reinterpret_cast<uint4*>(&Bsm[p][col][kq * 8]) = v;
  }
  __syncthreads();  // the ONLY barrier

  // bias registers (loop-invariant)
  float bir, biz, bin, bhr, bhz, bhn, bir2, biz2, bin2, bhr2, bhz2, bhn2;
  {
    int col = c0 + r;
    bir = gbih[col]; biz = gbih[col + 128]; bin = gbih[col + 256];
    bhr = gbhh[col]; bhz = gbhh[col + 128]; bhn = gbhh[col + 256];
    col += 16;
    bir2 = gbih[col]; biz2 = gbih[col + 128]; bin2 = gbih[col + 256];
    bhr2 = gbhh[col]; bhz2 = gbhh[col + 128]; bhn2 = gbhh[col + 256];
  }

  const int t0 = g * MT;
  const int tend = (t0 + MT < nt) ? t0 + MT : nt;

  short8 a1[4], a2[4], n1[4], n2[4];
  {
    int arow = t0 * 64 + (w << 4) + r;
    int ar = arow < nrows ? arow : nrows - 1;
    const unsigned short* Aa = xaggb + (size_t)ar * HD + q * 8;
    const unsigned short* Ax = xb + (size_t)ar * HD + q * 8;
#pragma unroll
    for (int ks = 0; ks < 4; ++ks) {
      a1[ks] = *reinterpret_cast<const short8*>(Aa + ks * 32);
      a2[ks] = *reinterpret_cast<const short8*>(Ax + ks * 32);
    }
  }

  for (int t = t0; t < tend; ++t) {
    // prefetch next tile's A fragments (overlaps with MFMA below)
    if (t + 1 < tend) {
      int arow = (t + 1) * 64 + (w << 4) + r;
      int ar = arow < nrows ? arow : nrows - 1;
      const unsigned short* Aa = xaggb + (size_t)ar * HD + q * 8;
      const unsigned short* Ax = xb + (size_t)ar * HD + q * 8;
#pragma unroll
      for (int ks = 0; ks < 4; ++ks) {
        n1[ks] = *reinterpret_cast<const short8*>(Aa + ks * 32);
        n2[ks] = *reinterpret_cast<const short8*>(Ax + ks * 32);
      }
    }

    f32x4 acc[6][2];
#pragma unroll
    for (int p = 0; p < 6; ++p)
#pragma unroll
      for (int cb = 0; cb < 2; ++cb) acc[p][cb] = (f32x4)0.f;

#pragma unroll
    for (int ks = 0; ks < 4; ++ks)
#pragma unroll
      for (int p = 0; p < 6; ++p) {
        short8 af = (p < 3) ? a1[ks] : a2[ks];
#pragma unroll
        for (int cb = 0; cb < 2; ++cb) {
          short8 bf = *reinterpret_cast<const short8*>(&Bsm[p][cb * 16 + r][ks * 32 + q * 8]);
          acc[p][cb] = __builtin_amdgcn_mfma_f32_16x16x32_bf16(af, bf, acc[p][cb], 0, 0, 0);
        }
      }

    const int row0 = t * 64;
#pragma unroll
    for (int cb = 0; cb < 2; ++cb) {
      int col = c0 + cb * 16 + r;
      float vir = cb ? bir2 : bir, viz = cb ? biz2 : biz, vin = cb ? bin2 : bin;
      float vhr = cb ? bhr2 : bhr, vhz = cb ? bhz2 : bhz, vhn = cb ? bhn2 : bhn;
#pragma unroll
      for (int reg = 0; reg < 4; ++reg) {
        int row = row0 + (w << 4) + q * 4 + reg;
        if (row < nrows) {
          float ir = acc[0][cb][reg] + vir, iz = acc[1][cb][reg] + viz;
          float inn = acc[2][cb][reg] + vin;
          float hr = acc[3][cb][reg] + vhr, hz = acc[4][cb][reg] + vhz;
          float hn = acc[5][cb][reg] + vhn;
          float rr = sigf(ir + hr), zz = sigf(iz + hz);
          float nn = tanhf_fast(inn + rr * hn);
          float xv = bf2f(xb[(size_t)row * HD + col]);
          hconv[(size_t)row * HD + col] = f2bf((1.f - zz) * nn + zz * xv);
        }
      }
    }

#pragma unroll
    for (int ks = 0; ks < 4; ++ks) { a1[ks] = n1[ks]; a2[ks] = n2[ks]; }
  }
}

// ---------------- fused LSTM: weights-resident, MT row-tiles per block ----------------
__global__ __launch_bounds__(256) void lstm_fused_k(
    const unsigned short* __restrict__ hconv, const unsigned short* __restrict__ lwb,
    const float* __restrict__ lbias, float* __restrict__ out, int nrows, int nt,
    int ngroups) {
  __shared__ unsigned short Bsm[3][32][136];
  const int id = blockIdx.x;
  const int rest = id >> 3;
  const int cg = rest & 3;
  const int g = ((rest >> 2) << 3) | (id & 7);
  if (g >= ngroups) return;
  const int tid = threadIdx.x;
  const int w = tid >> 6, lane = tid & 63;
  const int q = lane >> 4, r = lane & 15;
  const int c0 = cg * 32;

#pragma unroll
  for (int it = 0; it < 6; ++it) {
    int idx = it * 256 + tid;
    int p = idx >> 9, rem = idx & 511;
    int col = rem >> 4, kq = rem & 15;
    uint4 v = *reinterpret_cast<const uint4*>(
        lwb + ((size_t)(p * 128 + c0 + col)) * HD + kq * 8);
    *reinterpret_cast<uint4*>(&Bsm[p][col][kq * 8]) = v;
  }
  __syncthreads();  // the ONLY barrier

  float bi1, bg1, bo1, bi2, bg2, bo2;
  {
    int col = c0 + r;
    bi1 = lbias[col]; bg1 = lbias[col + 128]; bo1 = lbias[col + 256];
    col += 16;
    bi2 = lbias[col]; bg2 = lbias[col + 128]; bo2 = lbias[col + 256];
  }

  const int t0 = g * MT;
  const int tend = (t0 + MT < nt) ? t0 + MT : nt;

  short8 hp[4], np[4];
  {
    int arow = t0 * 64 + (w << 4) + r;
    int ar = arow < nrows ? arow : nrows - 1;
    const unsigned short* Ap = hconv + (size_t)ar * HD + q * 8;
#pragma unroll
    for (int ks = 0; ks < 4; ++ks)
      hp[ks] = *reinterpret_cast<const short8*>(Ap + ks * 32);
  }

  for (int t = t0; t < tend; ++t) {
    if (t + 1 < tend) {
      int arow = (t + 1) * 64 + (w << 4) + r;
      int ar = arow < nrows ? arow : nrows - 1;
      const unsigned short* Ap = hconv + (size_t)ar * HD + q * 8;
#pragma unroll
      for (int ks = 0; ks < 4; ++ks)
        np[ks] = *reinterpret_cast<const short8*>(Ap + ks * 32);
    }

    f32x4 acc[3][2];
#pragma unroll
    for (int p = 0; p < 3; ++p)
#pragma unroll
      for (int cb = 0; cb < 2; ++cb) acc[p][cb] = (f32x4)0.f;

#pragma unroll
    for (int ks = 0; ks < 4; ++ks)
#pragma unroll
      for (int p = 0; p < 3; ++p)
#pragma unroll
        for (int cb = 0; cb < 2; ++cb) {
          short8 bf = *reinterpret_cast<const short8*>(&Bsm[p][cb * 16 + r][ks * 32 + q * 8]);
          acc[p][cb] = __builtin_amdgcn_mfma_f32_16x16x32_bf16(hp[ks], bf, acc[p][cb], 0, 0, 0);
        }

    const int row0 = t * 64;
#pragma unroll
    for (int cb = 0; cb < 2; ++cb) {
      int col = c0 + cb * 16 + r;
      float bi = cb ? bi2 : bi1, bg = cb ? bg2 : bg1, bo = cb ? bo2 : bo1;
#pragma unroll
      for (int reg = 0; reg < 4; ++reg) {
        int row = row0 + (w << 4) + q * 4 + reg;
        if (row < nrows) {
          float ig = acc[0][cb][reg] + bi;
          float gg = acc[1][cb][reg] + bg;
          float og = acc[2][cb][reg] + bo;
          float cc = sigf(ig) * tanhf_fast(gg);
          out[(size_t)row * HD + col] = fmaxf(sigf(og) * tanhf_fast(cc), 0.f);
        }
      }
    }

#pragma unroll
    for (int ks = 0; ks < 4; ++ks) hp[ks] = np[ks];
  }
}

// ---------------- host ----------------

extern "C" void kernel_launch(void* const* d_in, const int* in_sizes, int n_in,
                              void* d_out, int out_size, void* d_ws, size_t ws_size,
                              hipStream_t stream) {
  const float* x = (const float*)d_in[0];
  const int* ei = (const int*)d_in[1];
  const float* W = (const float*)d_in[2];
  const float* gw_ih = (const float*)d_in[3];
  const float* gw_hh = (const float*)d_in[4];
  const float* gb_ih = (const float*)d_in[5];
  const float* gb_hh = (const float*)d_in[6];
  const float* lw_ih = (const float*)d_in[7];
  const float* lb_ih = (const float*)d_in[9];
  const float* lb_hh = (const float*)d_in[10];
  float* out = (float*)d_out;

  const int N = in_sizes[0] / HD;
  const int E = in_sizes[1] / 2;
  const size_t nH = (size_t)N * HD;

  int shift = 9;
  while (((N + (1 << shift) - 1) >> shift) > 256) ++shift;
  const int NB = (N + (1 << shift) - 1) >> shift;
  const int sbits = 32 - shift;

  const size_t N4p = (size_t)((N + 1 + 7) & ~7);  // rowstart: N+1
  const size_t E4 = (size_t)((E + 3) & ~3);
  const size_t BC = (size_t)NB * PB + 8;
  const int sc_total = NB * PB;
  const int sc_nblk = (sc_total + SCB - 1) / SCB;

  // ws layout: [rowstart][bcnt][bsums][csr][ebuf|xb][hconv|x8][Bpb][gwhhb][lwb][lbias]
  char* p = (char*)d_ws;
  int* rowstart = (int*)p;  p += 4 * N4p;
  int* bcnt = (int*)p;      p += 4 * BC;
  int* bsums = (int*)p;     p += 4 * 64;
  int* csr = (int*)p;       p += 4 * E4;
  size_t sz_eb = 4 * E4, sz_xb = 2 * nH;
  unsigned* ebuf = (unsigned*)p;            // dead after bfill2_k
  unsigned short* xb = (unsigned short*)p;  // written by convx_k after
  p += (sz_eb > sz_xb ? sz_eb : sz_xb);
  unsigned short* hconv = (unsigned short*)p;  p += 2 * nH;
  unsigned short* Bpb = (unsigned short*)p;    p += 2 * 49152;
  unsigned short* gwhhb = (unsigned short*)p;  p += 2 * 49152;
  unsigned short* lwb = (unsigned short*)p;    p += 2 * 49152;
  float* lbias = (float*)p;                    p += 4 * 384;

  // fp8 x table aliases hconv region (hconv first written by gru_fused_k,
  // which runs after gather_f8_k has fully consumed x8). nH bytes <= 2*nH.
  unsigned* x8 = (unsigned*)hconv;

  unsigned short* xaggb = (unsigned short*)d_out;  // consumed before out written

  dim3 blk(256);
  unsigned rb = (unsigned)((N + 63) / 64);
  int ngroups = (int)((rb + MT - 1) / MT);
  unsigned g8 = (unsigned)((ngroups + 7) & ~7);  // padded for the XCD swizzle decode

  // CSR build (bucketed)
  bcount_k<<<PB, blk, 0, stream>>>(ei, bcnt, E, N, shift, NB);
  scan1_k<<<sc_nblk, blk, 0, stream>>>(bcnt, bsums, sc_total);
  scan2_k<<<1, blk, 0, stream>>>(bsums, sc_nblk);
  scan3_k<<<sc_nblk, blk, 0, stream>>>(bcnt, bsums, sc_total, sc_nblk);
  bpart_k<<<PB, blk, 0, stream>>>(ei, bcnt, ebuf, E, N, shift, NB, sbits);
  bfill2_k<<<NB, blk, 0, stream>>>(ebuf, bcnt, rowstart, csr, N, shift, NB, sbits);

  // conversions + weight folds (separate kernels; xb overwrites dead ebuf)
  convx_k<<<(unsigned)((nH / 4 + 255) / 256), blk, 0, stream>>>(x, xb, x8, (int)(nH / 4));
  prepw_k<<<(2 * 49152 + 384 + 255) / 256, blk, 0, stream>>>(
      gw_hh, lw_ih, lb_ih, lb_hh, gwhhb, lwb, lbias);
  prepbp_k<<<192, blk, 0, stream>>>(W, gw_ih, Bpb);

  // aggregation (fp8 source rows, 128B/edge), split into 2 row-range dispatches
  // so sub-45us kernels stay visible in the profile top-5.
  int half = N / 2;
  {
    long long gt0 = (long long)half * 64;
    gather_f8_k<<<(unsigned)((gt0 + 255) / 256), blk, 0, stream>>>(
        csr, rowstart, x8, xaggb, 0, half);
    long long gt1 = (long long)(N - half) * 64;
    gather_f8_k<<<(unsigned)((gt1 + 255) / 256), blk, 0, stream>>>(
        csr, rowstart, x8, xaggb, half, N);
  }

  // hconv = GRU(xagg, x) with W folded into the input-gate weight
  gru_fused_k<<<4 * g8, blk, 0, stream>>>(
      xaggb, xb, Bpb, gwhhb, gb_ih, gb_hh, hconv, N, (int)rb, ngroups);

  // out = LSTM(hconv)
  lstm_fused_k<<<4 * g8, blk, 0, stream>>>(hconv, lwb, lbias, out, N, (int)rb, ngroups);
}

// Round 12
// 447.724 us; speedup vs baseline: 1.1082x; 1.1082x over previous
//
#include <hip/hip_runtime.h>
#include <math.h>

#define HD 128
#define PB 512   // partition blocks for bucketed CSR build (2 blocks/CU)
#define SCB 4096 // elements per block in multi-block scan

typedef __attribute__((ext_vector_type(8))) short short8;
typedef __attribute__((ext_vector_type(4))) float f32x4;
typedef __attribute__((ext_vector_type(2))) float f32x2;
typedef __attribute__((ext_vector_type(4))) unsigned u32x4;

__device__ __forceinline__ float sigf(float v) { return 1.0f / (1.0f + __expf(-v)); }
// tanh(x) = 1 - 2/(e^{2x}+1); exact to ~1e-7 rel, saturates correctly. Avoids libm tanhf.
__device__ __forceinline__ float tanhf_fast(float v) {
  float e = __expf(2.0f * v);
  return 1.0f - 2.0f / (e + 1.0f);
}

__device__ __forceinline__ unsigned short f2bf(float f) {
  union { float f; unsigned u; } v; v.f = f;
  unsigned r = (v.u + 0x7fffu + ((v.u >> 16) & 1u)) >> 16;
  return (unsigned short)r;
}
__device__ __forceinline__ float bf2f(unsigned short b) {
  union { unsigned u; float f; } v; v.u = ((unsigned)b) << 16;
  return v.f;
}

// ---------------- CSR build ----------------

__global__ __launch_bounds__(256) void bcount_k(const int* __restrict__ ei,
                                                int* __restrict__ bcnt,
                                                int E, int N, int shift, int NB) {
  __shared__ int h[256];
  const int blk = blockIdx.x, tid = threadIdx.x;
  h[tid] = 0;
  __syncthreads();
  int per = (E + PB - 1) / PB;
  int lo = blk * per;
  int hi = (lo + per < E) ? lo + per : E;
  for (int e = lo + tid; e < hi; e += 256) {
    int d = ei[(size_t)E + e];
    if ((unsigned)d >= (unsigned)N) continue;
    atomicAdd(&h[d >> shift], 1);
  }
  __syncthreads();
  if (tid < NB) bcnt[tid * PB + blk] = h[tid];
}

__global__ __launch_bounds__(256) void scan1_k(const int* __restrict__ a,
                                               int* __restrict__ bsums, int total) {
  __shared__ int ts[256];
  int b = blockIdx.x, tid = threadIdx.x;
  int lo = b * SCB + tid * 16;
  int s = 0;
#pragma unroll
  for (int i = 0; i < 16; ++i) {
    int idx = lo + i;
    if (idx < total) s += a[idx];
  }
  ts[tid] = s;
  __syncthreads();
  for (int off = 128; off > 0; off >>= 1) {
    if (tid < off) ts[tid] += ts[tid + off];
    __syncthreads();
  }
  if (tid == 0) bsums[b] = ts[0];
}

__global__ __launch_bounds__(256) void scan2_k(int* __restrict__ bsums, int nb) {
  __shared__ int ts[256];
  int tid = threadIdx.x;
  int v = (tid < nb) ? bsums[tid] : 0;
  ts[tid] = v;
  __syncthreads();
  for (int off = 1; off < 256; off <<= 1) {
    int u = (tid >= off) ? ts[tid - off] : 0;
    __syncthreads();
    ts[tid] += u;
    __syncthreads();
  }
  if (tid < nb) bsums[tid] = ts[tid] - v;  // exclusive
}

__global__ __launch_bounds__(256) void scan3_k(int* __restrict__ a,
                                               const int* __restrict__ bsums,
                                               int total, int nblk) {
  __shared__ int ts[256];
  int b = blockIdx.x, tid = threadIdx.x;
  int lo = b * SCB + tid * 16;
  int pre[16];
  int s = 0;
#pragma unroll
  for (int i = 0; i < 16; ++i) {
    int idx = lo + i;
    int xv = (idx < total) ? a[idx] : 0;
    pre[i] = s;
    s += xv;
  }
  ts[tid] = s;
  __syncthreads();
  for (int off = 1; off < 256; off <<= 1) {
    int u = (tid >= off) ? ts[tid - off] : 0;
    __syncthreads();
    ts[tid] += u;
    __syncthreads();
  }
  int off0 = ts[tid] - s + bsums[b];
#pragma unroll
  for (int i = 0; i < 16; ++i) {
    int idx = lo + i;
    if (idx < total) a[idx] = off0 + pre[i];
  }
  if (b == nblk - 1 && tid == 255) a[total] = off0 + s;  // grand total
}

__global__ __launch_bounds__(256) void bpart_k(const int* __restrict__ ei,
                                               const int* __restrict__ bstart,
                                               unsigned* __restrict__ ebuf,
                                               int E, int N, int shift, int NB,
                                               int sbits) {
  __shared__ int cur[256];
  const int blk = blockIdx.x, tid = threadIdx.x;
  if (tid < NB) cur[tid] = bstart[tid * PB + blk];
  __syncthreads();
  int per = (E + PB - 1) / PB;
  int lo = blk * per;
  int hi = (lo + per < E) ? lo + per : E;
  const unsigned dmask = (1u << shift) - 1u;
  for (int e = lo + tid; e < hi; e += 256) {
    int s = ei[e];
    int d = ei[(size_t)E + e];
    if ((unsigned)s >= (unsigned)N || (unsigned)d >= (unsigned)N) continue;
    int p = atomicAdd(&cur[d >> shift], 1);
    ebuf[p] = (((unsigned)d & dmask) << sbits) | (unsigned)s;
  }
}

__global__ __launch_bounds__(256) void bfill2_k(const unsigned* __restrict__ ebuf,
                                                const int* __restrict__ bstart,
                                                int* __restrict__ rowstart,
                                                int* __restrict__ csr,
                                                int N, int shift, int NB, int sbits) {
  __shared__ int cnt[2048];
  __shared__ int tsum[256];
  const int b = blockIdx.x, tid = threadIdx.x;
  const int d0 = b << shift;
  int dmax = d0 + (1 << shift);
  if (dmax > N) dmax = N;
  const int nd = dmax - d0;
  const unsigned smask = (1u << sbits) - 1u;
  for (int i = tid; i < nd; i += 256) cnt[i] = 0;
  __syncthreads();
  const int base = bstart[b * PB];
  const int end = bstart[(b + 1) * PB];  // b=NB-1 -> bstart[NB*PB] = grand total
  for (int idx = base + tid; idx < end; idx += 256)
    atomicAdd(&cnt[ebuf[idx] >> sbits], 1);
  __syncthreads();
  const int C = (nd + 255) / 256;  // <= 8
  int lo = tid * C;
  int hi = (lo + C < nd) ? lo + C : nd;
  int loc[8];
  int s = 0;
  for (int i = lo; i < hi; ++i) {
    loc[i - lo] = cnt[i];
    s += cnt[i];
  }
  tsum[tid] = s;
  __syncthreads();
  for (int off = 1; off < 256; off <<= 1) {
    int u = (tid >= off) ? tsum[tid - off] : 0;
    __syncthreads();
    tsum[tid] += u;
    __syncthreads();
  }
  int run = tsum[tid] - s + base;
  for (int i = lo; i < hi; ++i) {
    rowstart[d0 + i] = run;
    cnt[i] = run;  // becomes the cursor
    run += loc[i - lo];
  }
  if (b == NB - 1 && tid == 255) rowstart[N] = end;
  __syncthreads();
  for (int idx = base + tid; idx < end; idx += 256) {
    unsigned pk = ebuf[idx];
    int p = atomicAdd(&cnt[pk >> sbits], 1);
    csr[p] = (int)(pk & smask);
  }
}

// ---------------- conversions (separate kernels) ----------------

__global__ __launch_bounds__(256) void convx_k(const float* __restrict__ x,
                                               unsigned short* __restrict__ xb,
                                               unsigned* __restrict__ x8, int n4) {
  int t = blockIdx.x * 256 + threadIdx.x;
  if (t >= n4) return;
  float4 v = reinterpret_cast<const float4*>(x)[t];
  ushort4 o;
  o.x = f2bf(v.x); o.y = f2bf(v.y); o.z = f2bf(v.z); o.w = f2bf(v.w);
  reinterpret_cast<ushort4*>(xb)[t] = o;
  int p8 = 0;
  p8 = __builtin_amdgcn_cvt_pk_fp8_f32(v.x, v.y, p8, false);  // bytes 0,1
  p8 = __builtin_amdgcn_cvt_pk_fp8_f32(v.z, v.w, p8, true);   // bytes 2,3
  x8[t] = (unsigned)p8;
}

__global__ __launch_bounds__(256) void prepw_k(
    const float* __restrict__ gwhh, const float* __restrict__ lwih,
    const float* __restrict__ lbih, const float* __restrict__ lbhh,
    unsigned short* __restrict__ gwhhb, unsigned short* __restrict__ lwb,
    float* __restrict__ lbias) {
  int t = blockIdx.x * 256 + threadIdx.x;
  if (t < 49152) { gwhhb[t] = f2bf(gwhh[t]); return; }
  t -= 49152;
  if (t < 49152) {  // select i,g,o rows of [512,128]
    int j = t >> 7, k = t & 127;
    int jm = j < 128 ? j : j + 128;
    lwb[t] = f2bf(lwih[(size_t)jm * 128 + k]);
    return;
  }
  t -= 49152;
  if (t < 384) {
    int jm = t < 128 ? t : t + 128;
    lbias[t] = lbih[jm] + lbhh[jm];
  }
}

// Bp[j,k] = sum_c W[k,c] * gwih[j,c]  (fold of conv-W into GRU input weight)
__global__ __launch_bounds__(256) void prepbp_k(const float* __restrict__ W,
                                                const float* __restrict__ gwih,
                                                unsigned short* __restrict__ Bpb) {
  int t = blockIdx.x * 256 + threadIdx.x;
  if (t >= 49152) return;
  int j = t >> 7, k = t & 127;
  const float4* wr = reinterpret_cast<const float4*>(W + (size_t)k * 128);
  const float4* gr = reinterpret_cast<const float4*>(gwih + (size_t)j * 128);
  float acc = 0.f;
#pragma unroll
  for (int c = 0; c < 32; ++c) {
    float4 a = wr[c], b = gr[c];
    acc += a.x * b.x + a.y * b.y + a.z * b.z + a.w * b.w;
  }
  Bpb[t] = f2bf(acc);
}

// ---------------- gather (fp8 in, bf16 out) — r1 structure, row-range split ----------------
// Bound by random-transaction rate (~40G/s): 1 transaction/edge is the floor.
__device__ __forceinline__ void accf8(f32x2* acc, uint4 v) {
  acc[0] += __builtin_amdgcn_cvt_pk_f32_fp8((int)v.x, false);
  acc[1] += __builtin_amdgcn_cvt_pk_f32_fp8((int)v.x, true);
  acc[2] += __builtin_amdgcn_cvt_pk_f32_fp8((int)v.y, false);
  acc[3] += __builtin_amdgcn_cvt_pk_f32_fp8((int)v.y, true);
  acc[4] += __builtin_amdgcn_cvt_pk_f32_fp8((int)v.z, false);
  acc[5] += __builtin_amdgcn_cvt_pk_f32_fp8((int)v.z, true);
  acc[6] += __builtin_amdgcn_cvt_pk_f32_fp8((int)v.w, false);
  acc[7] += __builtin_amdgcn_cvt_pk_f32_fp8((int)v.w, true);
}

__global__ __launch_bounds__(256) void gather_f8_k(const int* __restrict__ csr,
                                                   const int* __restrict__ rowstart,
                                                   const unsigned* __restrict__ x8,
                                                   unsigned short* __restrict__ xaggb,
                                                   int row0, int rowend) {
  int w = row0 + (int)(((long long)blockIdx.x * 256 + threadIdx.x) >> 6);
  if (w >= rowend) return;
  const int lane = threadIdx.x & 63;
  const int sub = lane >> 3, li = lane & 7;
  const int beg = rowstart[w], end = rowstart[w + 1];
  const uint4* x4 = reinterpret_cast<const uint4*>(x8);  // row = 8 uint4 (128B)

  f32x2 acc[8];
#pragma unroll
  for (int i = 0; i < 8; ++i) acc[i] = (f32x2)0.f;

  int j = beg;
  for (; j + 16 <= end; j += 16) {
    int s0 = __builtin_nontemporal_load(&csr[j + sub]);
    int s1 = __builtin_nontemporal_load(&csr[j + 8 + sub]);
    uint4 v0 = x4[(size_t)s0 * 8 + li];
    uint4 v1 = x4[(size_t)s1 * 8 + li];
    accf8(acc, v0);
    accf8(acc, v1);
  }
  for (; j + 8 <= end; j += 8) {
    int s0 = __builtin_nontemporal_load(&csr[j + sub]);
    uint4 v0 = x4[(size_t)s0 * 8 + li];
    accf8(acc, v0);
  }
  int rem = end - j;  // 0..7
  if (sub < rem) {
    int s0 = csr[j + sub];
    uint4 v0 = x4[(size_t)s0 * 8 + li];
    accf8(acc, v0);
  }

  float a16[16];
#pragma unroll
  for (int i = 0; i < 8; ++i) { a16[2 * i] = acc[i].x; a16[2 * i + 1] = acc[i].y; }
#pragma unroll
  for (int i = 0; i < 16; ++i) {
    a16[i] += __shfl_xor(a16[i], 8, 64);
    a16[i] += __shfl_xor(a16[i], 16, 64);
    a16[i] += __shfl_xor(a16[i], 32, 64);
  }

  if (lane < 8) {
    float scale = 1.0f / fmaxf((float)(end - beg), 1.0f);
    u32x4 o1, o2;
    o1.x = (unsigned)f2bf(a16[0] * scale) | ((unsigned)f2bf(a16[1] * scale) << 16);
    o1.y = (unsigned)f2bf(a16[2] * scale) | ((unsigned)f2bf(a16[3] * scale) << 16);
    o1.z = (unsigned)f2bf(a16[4] * scale) | ((unsigned)f2bf(a16[5] * scale) << 16);
    o1.w = (unsigned)f2bf(a16[6] * scale) | ((unsigned)f2bf(a16[7] * scale) << 16);
    o2.x = (unsigned)f2bf(a16[8] * scale) | ((unsigned)f2bf(a16[9] * scale) << 16);
    o2.y = (unsigned)f2bf(a16[10] * scale) | ((unsigned)f2bf(a16[11] * scale) << 16);
    o2.z = (unsigned)f2bf(a16[12] * scale) | ((unsigned)f2bf(a16[13] * scale) << 16);
    o2.w = (unsigned)f2bf(a16[14] * scale) | ((unsigned)f2bf(a16[15] * scale) << 16);
    u32x4* dst = reinterpret_cast<u32x4*>(xaggb + (size_t)w * HD) + li * 2;
    dst[0] = o1;   // cached stores: downstream gru reads can hit cache
    dst[1] = o2;
  }
}

// ---------------- fused GRU: r10-proven structure, XCD-swizzled, row-range split ----------------
// Two-stage staging (26KB LDS), grid 4 col-groups x tiles. XCD swizzle keeps the
// 4 col-blocks of a tile on one XCD (r10: FETCH 119->26MB). Row-range split into
// two dispatches (~37us each) lowers the profile top-5 threshold so lstm / CSR
// kernels become visible. r11's weights-resident MT loop is reverted (VGPR 168,
// occ 8.4%, 117us — register-bound regression).
__global__ __launch_bounds__(256) void gru_fused_k(
    const unsigned short* __restrict__ xaggb, const unsigned short* __restrict__ xb,
    const unsigned short* __restrict__ Bpb, const unsigned short* __restrict__ gwhhb,
    const float* __restrict__ gbih, const float* __restrict__ gbhh,
    unsigned short* __restrict__ hconv, int nrows, int tbase, int ntl) {
  __shared__ unsigned short Bsm[3][32][136];
  const int id = blockIdx.x;
  const int rest = id >> 3;
  const int cg = rest & 3;
  const int tl = ((rest >> 2) << 3) | (id & 7);
  if (tl >= ntl) return;  // uniform over block (before any barrier)
  const int t = tbase + tl;
  const int tid = threadIdx.x;
  const int w = tid >> 6, lane = tid & 63;
  const int q = lane >> 4, r = lane & 15;
  const int row0 = t * 64;
  const int c0 = cg * 32;

  // A fragments (issued early; global latency hides under staging)
  int arow = row0 + (w << 4) + r;
  int ar = arow < nrows ? arow : nrows - 1;
  const unsigned short* Aa = xaggb + (size_t)ar * HD + q * 8;
  const unsigned short* Ax = xb + (size_t)ar * HD + q * 8;
  short8 a1[4], a2[4];
#pragma unroll
  for (int ks = 0; ks < 4; ++ks) {
    a1[ks] = *reinterpret_cast<const short8*>(Aa + ks * 32);
    a2[ks] = *reinterpret_cast<const short8*>(Ax + ks * 32);
  }

  f32x4 acc[6][2];
#pragma unroll
  for (int p = 0; p < 6; ++p)
#pragma unroll
    for (int cb = 0; cb < 2; ++cb) acc[p][cb] = (f32x4)0.f;

  // ---- stage set 0: Bp planes (ir, iz, in) ----
#pragma unroll
  for (int it = 0; it < 6; ++it) {
    int idx = it * 256 + tid;
    int p = idx >> 9, rem = idx & 511;
    int col = rem >> 4, kq = rem & 15;
    uint4 v = *reinterpret_cast<const uint4*>(
        Bpb + ((size_t)(p * 128 + c0 + col)) * HD + kq * 8);
    *reinterpret_cast<uint4*>(&Bsm[p][col][kq * 8]) = v;
  }
  __syncthreads();
#pragma unroll
  for (int ks = 0; ks < 4; ++ks)
#pragma unroll
    for (int p = 0; p < 3; ++p)
#pragma unroll
      for (int cb = 0; cb < 2; ++cb) {
        short8 bf = *reinterpret_cast<const short8*>(&Bsm[p][cb * 16 + r][ks * 32 + q * 8]);
        acc[p][cb] = __builtin_amdgcn_mfma_f32_16x16x32_bf16(a1[ks], bf, acc[p][cb], 0, 0, 0);
      }
  __syncthreads();

  // ---- stage set 1: gwhh planes (hr, hz, hn) ----
#pragma unroll
  for (int it = 0; it < 6; ++it) {
    int idx = it * 256 + tid;
    int p = idx >> 9, rem = idx & 511;
    int col = rem >> 4, kq = rem & 15;
    uint4 v = *reinterpret_cast<const uint4*>(
        gwhhb + ((size_t)(p * 128 + c0 + col)) * HD + kq * 8);
    *reinterpret_cast<uint4*>(&Bsm[p][col][kq * 8]) = v;
  }
  __syncthreads();
#pragma unroll
  for (int ks = 0; ks < 4; ++ks)
#pragma unroll
    for (int p = 0; p < 3; ++p)
#pragma unroll
      for (int cb = 0; cb < 2; ++cb) {
        short8 bf = *reinterpret_cast<const short8*>(&Bsm[p][cb * 16 + r][ks * 32 + q * 8]);
        acc[3 + p][cb] = __builtin_amdgcn_mfma_f32_16x16x32_bf16(a2[ks], bf, acc[3 + p][cb], 0, 0, 0);
      }

  // ---- epilogue ----
#pragma unroll
  for (int cb = 0; cb < 2; ++cb) {
    int col = c0 + cb * 16 + r;
    float bir = gbih[col], biz = gbih[col + 128], bin = gbih[col + 256];
    float bhr = gbhh[col], bhz = gbhh[col + 128], bhn = gbhh[col + 256];
#pragma unroll
    for (int reg = 0; reg < 4; ++reg) {
      int row = row0 + (w << 4) + q * 4 + reg;
      if (row < nrows) {
        float ir = acc[0][cb][reg] + bir, iz = acc[1][cb][reg] + biz;
        float inn = acc[2][cb][reg] + bin;
        float hr = acc[3][cb][reg] + bhr, hz = acc[4][cb][reg] + bhz;
        float hn = acc[5][cb][reg] + bhn;
        float rr = sigf(ir + hr), zz = sigf(iz + hz);
        float nn = tanhf_fast(inn + rr * hn);
        float xv = bf2f(xb[(size_t)row * HD + col]);
        hconv[(size_t)row * HD + col] = f2bf((1.f - zz) * nn + zz * xv);
      }
    }
  }
}

// ---------------- fused LSTM: 32-col blocks, XCD-swizzled 1D grid (r10) ----------------
__global__ __launch_bounds__(256) void lstm_fused_k(
    const unsigned short* __restrict__ hconv, const unsigned short* __restrict__ lwb,
    const float* __restrict__ lbias, float* __restrict__ out, int nrows, int nt) {
  __shared__ unsigned short Bsm[3][32][136];
  const int id = blockIdx.x;
  const int rest = id >> 3;
  const int cg = rest & 3;
  const int t = ((rest >> 2) << 3) | (id & 7);
  if (t >= nt) return;
  const int tid = threadIdx.x;
  const int w = tid >> 6, lane = tid & 63;
  const int q = lane >> 4, r = lane & 15;
  const int row0 = t * 64;
  const int c0 = cg * 32;

  int arow = row0 + (w << 4) + r;
  int ar = arow < nrows ? arow : nrows - 1;
  const unsigned short* Ap = hconv + (size_t)ar * HD + q * 8;
  short8 hp[4];
#pragma unroll
  for (int ks = 0; ks < 4; ++ks)
    hp[ks] = *reinterpret_cast<const short8*>(Ap + ks * 32);

#pragma unroll
  for (int it = 0; it < 6; ++it) {
    int idx = it * 256 + tid;
    int p = idx >> 9, rem = idx & 511;
    int col = rem >> 4, kq = rem & 15;
    uint4 v = *reinterpret_cast<const uint4*>(
        lwb + ((size_t)(p * 128 + c0 + col)) * HD + kq * 8);
    *reinterpret_cast<uint4*>(&Bsm[p][col][kq * 8]) = v;
  }
  __syncthreads();

  f32x4 acc[3][2];
#pragma unroll
  for (int p = 0; p < 3; ++p)
#pragma unroll
    for (int cb = 0; cb < 2; ++cb) acc[p][cb] = (f32x4)0.f;

#pragma unroll
  for (int ks = 0; ks < 4; ++ks)
#pragma unroll
    for (int p = 0; p < 3; ++p)
#pragma unroll
      for (int cb = 0; cb < 2; ++cb) {
        short8 bf = *reinterpret_cast<const short8*>(&Bsm[p][cb * 16 + r][ks * 32 + q * 8]);
        acc[p][cb] = __builtin_amdgcn_mfma_f32_16x16x32_bf16(hp[ks], bf, acc[p][cb], 0, 0, 0);
      }

#pragma unroll
  for (int cb = 0; cb < 2; ++cb) {
    int col = c0 + cb * 16 + r;
    float bi = lbias[col], bg = lbias[col + 128], bo = lbias[col + 256];
#pragma unroll
    for (int reg = 0; reg < 4; ++reg) {
      int row = row0 + (w << 4) + q * 4 + reg;
      if (row < nrows) {
        float ig = acc[0][cb][reg] + bi;
        float gg = acc[1][cb][reg] + bg;
        float og = acc[2][cb][reg] + bo;
        float cc = sigf(ig) * tanhf_fast(gg);
        out[(size_t)row * HD + col] = fmaxf(sigf(og) * tanhf_fast(cc), 0.f);
      }
    }
  }
}

// ---------------- host ----------------

extern "C" void kernel_launch(void* const* d_in, const int* in_sizes, int n_in,
                              void* d_out, int out_size, void* d_ws, size_t ws_size,
                              hipStream_t stream) {
  const float* x = (const float*)d_in[0];
  const int* ei = (const int*)d_in[1];
  const float* W = (const float*)d_in[2];
  const float* gw_ih = (const float*)d_in[3];
  const float* gw_hh = (const float*)d_in[4];
  const float* gb_ih = (const float*)d_in[5];
  const float* gb_hh = (const float*)d_in[6];
  const float* lw_ih = (const float*)d_in[7];
  const float* lb_ih = (const float*)d_in[9];
  const float* lb_hh = (const float*)d_in[10];
  float* out = (float*)d_out;

  const int N = in_sizes[0] / HD;
  const int E = in_sizes[1] / 2;
  const size_t nH = (size_t)N * HD;

  int shift = 9;
  while (((N + (1 << shift) - 1) >> shift) > 256) ++shift;
  const int NB = (N + (1 << shift) - 1) >> shift;
  const int sbits = 32 - shift;

  const size_t N4p = (size_t)((N + 1 + 7) & ~7);  // rowstart: N+1
  const size_t E4 = (size_t)((E + 3) & ~3);
  const size_t BC = (size_t)NB * PB + 8;
  const int sc_total = NB * PB;
  const int sc_nblk = (sc_total + SCB - 1) / SCB;

  // ws layout: [rowstart][bcnt][bsums][csr][ebuf|xb][hconv|x8][Bpb][gwhhb][lwb][lbias]
  char* p = (char*)d_ws;
  int* rowstart = (int*)p;  p += 4 * N4p;
  int* bcnt = (int*)p;      p += 4 * BC;
  int* bsums = (int*)p;     p += 4 * 64;
  int* csr = (int*)p;       p += 4 * E4;
  size_t sz_eb = 4 * E4, sz_xb = 2 * nH;
  unsigned* ebuf = (unsigned*)p;            // dead after bfill2_k
  unsigned short* xb = (unsigned short*)p;  // written by convx_k after
  p += (sz_eb > sz_xb ? sz_eb : sz_xb);
  unsigned short* hconv = (unsigned short*)p;  p += 2 * nH;
  unsigned short* Bpb = (unsigned short*)p;    p += 2 * 49152;
  unsigned short* gwhhb = (unsigned short*)p;  p += 2 * 49152;
  unsigned short* lwb = (unsigned short*)p;    p += 2 * 49152;
  float* lbias = (float*)p;                    p += 4 * 384;

  // fp8 x table aliases hconv region (hconv first written by gru_fused_k,
  // which runs after gather_f8_k has fully consumed x8). nH bytes <= 2*nH.
  unsigned* x8 = (unsigned*)hconv;

  unsigned short* xaggb = (unsigned short*)d_out;  // consumed before out written

  dim3 blk(256);
  unsigned rb = (unsigned)((N + 63) / 64);
  unsigned rb8 = (rb + 7) & ~7u;  // padded so the swizzle decode covers all tiles

  // CSR build (bucketed)
  bcount_k<<<PB, blk, 0, stream>>>(ei, bcnt, E, N, shift, NB);
  scan1_k<<<sc_nblk, blk, 0, stream>>>(bcnt, bsums, sc_total);
  scan2_k<<<1, blk, 0, stream>>>(bsums, sc_nblk);
  scan3_k<<<sc_nblk, blk, 0, stream>>>(bcnt, bsums, sc_total, sc_nblk);
  bpart_k<<<PB, blk, 0, stream>>>(ei, bcnt, ebuf, E, N, shift, NB, sbits);
  bfill2_k<<<NB, blk, 0, stream>>>(ebuf, bcnt, rowstart, csr, N, shift, NB, sbits);

  // conversions + weight folds (separate kernels; xb overwrites dead ebuf)
  convx_k<<<(unsigned)((nH / 4 + 255) / 256), blk, 0, stream>>>(x, xb, x8, (int)(nH / 4));
  prepw_k<<<(2 * 49152 + 384 + 255) / 256, blk, 0, stream>>>(
      gw_hh, lw_ih, lb_ih, lb_hh, gwhhb, lwb, lbias);
  prepbp_k<<<192, blk, 0, stream>>>(W, gw_ih, Bpb);

  // aggregation (fp8 source rows, 128B/edge), split into 2 row-range dispatches
  int half = N / 2;
  {
    long long gt0 = (long long)half * 64;
    gather_f8_k<<<(unsigned)((gt0 + 255) / 256), blk, 0, stream>>>(
        csr, rowstart, x8, xaggb, 0, half);
    long long gt1 = (long long)(N - half) * 64;
    gather_f8_k<<<(unsigned)((gt1 + 255) / 256), blk, 0, stream>>>(
        csr, rowstart, x8, xaggb, half, N);
  }

  // hconv = GRU(xagg, x), W folded into the input-gate weight.
  // Split into two tile-range dispatches (~37us each) for profile visibility.
  {
    int h0 = (int)((rb + 1) / 2);
    int h1 = (int)rb - h0;
    unsigned g0 = (unsigned)((h0 + 7) & ~7);
    unsigned g1 = (unsigned)((h1 + 7) & ~7);
    gru_fused_k<<<4 * g0, blk, 0, stream>>>(
        xaggb, xb, Bpb, gwhhb, gb_ih, gb_hh, hconv, N, 0, h0);
    gru_fused_k<<<4 * g1, blk, 0, stream>>>(
        xaggb, xb, Bpb, gwhhb, gb_ih, gb_hh, hconv, N, h0, h1);
  }

  // out = LSTM(hconv)
  lstm_fused_k<<<4 * rb8, blk, 0, stream>>>(hconv, lwb, lbias, out, N, (int)rb);
}

// Round 13
// 429.067 us; speedup vs baseline: 1.1564x; 1.0435x over previous
//
#include <hip/hip_runtime.h>
#include <math.h>

#define HD 128
#define PB 512   // partition blocks for bucketed CSR build (2 blocks/CU)
#define SCB 4096 // elements per block in multi-block scan

typedef __attribute__((ext_vector_type(8))) short short8;
typedef __attribute__((ext_vector_type(4))) float f32x4;
typedef __attribute__((ext_vector_type(2))) float f32x2;
typedef __attribute__((ext_vector_type(4))) unsigned u32x4;

__device__ __forceinline__ float sigf(float v) { return 1.0f / (1.0f + __expf(-v)); }
// tanh(x) = 1 - 2/(e^{2x}+1); exact to ~1e-7 rel, saturates correctly. Avoids libm tanhf.
__device__ __forceinline__ float tanhf_fast(float v) {
  float e = __expf(2.0f * v);
  return 1.0f - 2.0f / (e + 1.0f);
}

__device__ __forceinline__ unsigned short f2bf(float f) {
  union { float f; unsigned u; } v; v.f = f;
  unsigned r = (v.u + 0x7fffu + ((v.u >> 16) & 1u)) >> 16;
  return (unsigned short)r;
}
__device__ __forceinline__ float bf2f(unsigned short b) {
  union { unsigned u; float f; } v; v.u = ((unsigned)b) << 16;
  return v.f;
}

// ---------------- CSR build ----------------
// Launch-count matters: ~6-10us fixed cost per dispatch (r12: +1 dispatch = +7.4us
// total; gather split 2-way = +10us). CSR pipeline trimmed 6 -> 5 dispatches.

__global__ __launch_bounds__(256) void bcount_k(const int* __restrict__ ei,
                                                int* __restrict__ bcnt,
                                                int E, int N, int shift, int NB) {
  __shared__ int h[256];
  const int blk = blockIdx.x, tid = threadIdx.x;
  h[tid] = 0;
  __syncthreads();
  int per = (E + PB - 1) / PB;
  int lo = blk * per;
  int hi = (lo + per < E) ? lo + per : E;
  for (int e = lo + tid; e < hi; e += 256) {
    int d = ei[(size_t)E + e];
    if ((unsigned)d >= (unsigned)N) continue;
    atomicAdd(&h[d >> shift], 1);
  }
  __syncthreads();
  if (tid < NB) bcnt[tid * PB + blk] = h[tid];
}

__global__ __launch_bounds__(256) void scan1_k(const int* __restrict__ a,
                                               int* __restrict__ bsums, int total) {
  __shared__ int ts[256];
  int b = blockIdx.x, tid = threadIdx.x;
  int lo = b * SCB + tid * 16;
  int s = 0;
#pragma unroll
  for (int i = 0; i < 16; ++i) {
    int idx = lo + i;
    if (idx < total) s += a[idx];
  }
  ts[tid] = s;
  __syncthreads();
  for (int off = 128; off > 0; off >>= 1) {
    if (tid < off) ts[tid] += ts[tid + off];
    __syncthreads();
  }
  if (tid == 0) bsums[b] = ts[0];
}

// scan3 with scan2 folded in: every block LDS-scans the (<=32) bsums itself
// and picks its own exclusive prefix — saves the scan2 dispatch.
__global__ __launch_bounds__(256) void scan3_k(int* __restrict__ a,
                                               const int* __restrict__ bsums,
                                               int total, int nblk) {
  __shared__ int ts[256];
  __shared__ int boff_sm;
  int b = blockIdx.x, tid = threadIdx.x;

  // exclusive prefix of bsums at index b (redundant per block; nblk <= 32)
  int v = (tid < nblk) ? bsums[tid] : 0;
  ts[tid] = v;
  __syncthreads();
  for (int off = 1; off < 256; off <<= 1) {
    int u = (tid >= off) ? ts[tid - off] : 0;
    __syncthreads();
    ts[tid] += u;
    __syncthreads();
  }
  if (tid == b) boff_sm = ts[tid] - v;
  __syncthreads();
  const int boff = boff_sm;
  __syncthreads();  // ts reused below

  int lo = b * SCB + tid * 16;
  int pre[16];
  int s = 0;
#pragma unroll
  for (int i = 0; i < 16; ++i) {
    int idx = lo + i;
    int xv = (idx < total) ? a[idx] : 0;
    pre[i] = s;
    s += xv;
  }
  ts[tid] = s;
  __syncthreads();
  for (int off = 1; off < 256; off <<= 1) {
    int u = (tid >= off) ? ts[tid - off] : 0;
    __syncthreads();
    ts[tid] += u;
    __syncthreads();
  }
  int off0 = ts[tid] - s + boff;
#pragma unroll
  for (int i = 0; i < 16; ++i) {
    int idx = lo + i;
    if (idx < total) a[idx] = off0 + pre[i];
  }
  if (b == nblk - 1 && tid == 255) a[total] = off0 + s;  // grand total
}

__global__ __launch_bounds__(256) void bpart_k(const int* __restrict__ ei,
                                               const int* __restrict__ bstart,
                                               unsigned* __restrict__ ebuf,
                                               int E, int N, int shift, int NB,
                                               int sbits) {
  __shared__ int cur[256];
  const int blk = blockIdx.x, tid = threadIdx.x;
  if (tid < NB) cur[tid] = bstart[tid * PB + blk];
  __syncthreads();
  int per = (E + PB - 1) / PB;
  int lo = blk * per;
  int hi = (lo + per < E) ? lo + per : E;
  const unsigned dmask = (1u << shift) - 1u;
  for (int e = lo + tid; e < hi; e += 256) {
    int s = ei[e];
    int d = ei[(size_t)E + e];
    if ((unsigned)s >= (unsigned)N || (unsigned)d >= (unsigned)N) continue;
    int p = atomicAdd(&cur[d >> shift], 1);
    ebuf[p] = (((unsigned)d & dmask) << sbits) | (unsigned)s;
  }
}

__global__ __launch_bounds__(256) void bfill2_k(const unsigned* __restrict__ ebuf,
                                                const int* __restrict__ bstart,
                                                int* __restrict__ rowstart,
                                                int* __restrict__ csr,
                                                int N, int shift, int NB, int sbits) {
  __shared__ int cnt[2048];
  __shared__ int tsum[256];
  const int b = blockIdx.x, tid = threadIdx.x;
  const int d0 = b << shift;
  int dmax = d0 + (1 << shift);
  if (dmax > N) dmax = N;
  const int nd = dmax - d0;
  const unsigned smask = (1u << sbits) - 1u;
  for (int i = tid; i < nd; i += 256) cnt[i] = 0;
  __syncthreads();
  const int base = bstart[b * PB];
  const int end = bstart[(b + 1) * PB];  // b=NB-1 -> bstart[NB*PB] = grand total
  for (int idx = base + tid; idx < end; idx += 256)
    atomicAdd(&cnt[ebuf[idx] >> sbits], 1);
  __syncthreads();
  const int C = (nd + 255) / 256;  // <= 8
  int lo = tid * C;
  int hi = (lo + C < nd) ? lo + C : nd;
  int loc[8];
  int s = 0;
  for (int i = lo; i < hi; ++i) {
    loc[i - lo] = cnt[i];
    s += cnt[i];
  }
  tsum[tid] = s;
  __syncthreads();
  for (int off = 1; off < 256; off <<= 1) {
    int u = (tid >= off) ? tsum[tid - off] : 0;
    __syncthreads();
    tsum[tid] += u;
    __syncthreads();
  }
  int run = tsum[tid] - s + base;
  for (int i = lo; i < hi; ++i) {
    rowstart[d0 + i] = run;
    cnt[i] = run;  // becomes the cursor
    run += loc[i - lo];
  }
  if (b == NB - 1 && tid == 255) rowstart[N] = end;
  __syncthreads();
  for (int idx = base + tid; idx < end; idx += 256) {
    unsigned pk = ebuf[idx];
    int p = atomicAdd(&cnt[pk >> sbits], 1);
    csr[p] = (int)(pk & smask);
  }
}

// ---------------- conversions ----------------
// convx + prepw merged (both low-VGPR streamers). prepbp stays separate: its
// unrolled fp32 dot loop is the VGPR-heavy piece that sank r5's full fusion.

__global__ __launch_bounds__(256) void convprep_k(
    const float* __restrict__ x, unsigned short* __restrict__ xb,
    unsigned* __restrict__ x8,
    const float* __restrict__ gwhh, const float* __restrict__ lwih,
    const float* __restrict__ lbih, const float* __restrict__ lbhh,
    unsigned short* __restrict__ gwhhb, unsigned short* __restrict__ lwb,
    float* __restrict__ lbias, int n4) {
  int t = blockIdx.x * 256 + threadIdx.x;
  if (t < n4) {
    float4 v = reinterpret_cast<const float4*>(x)[t];
    ushort4 o;
    o.x = f2bf(v.x); o.y = f2bf(v.y); o.z = f2bf(v.z); o.w = f2bf(v.w);
    reinterpret_cast<ushort4*>(xb)[t] = o;
    int p8 = 0;
    p8 = __builtin_amdgcn_cvt_pk_fp8_f32(v.x, v.y, p8, false);  // bytes 0,1
    p8 = __builtin_amdgcn_cvt_pk_fp8_f32(v.z, v.w, p8, true);   // bytes 2,3
    x8[t] = (unsigned)p8;
    return;
  }
  t -= n4;
  if (t < 49152) { gwhhb[t] = f2bf(gwhh[t]); return; }
  t -= 49152;
  if (t < 49152) {  // select i,g,o rows of [512,128]
    int j = t >> 7, k = t & 127;
    int jm = j < 128 ? j : j + 128;
    lwb[t] = f2bf(lwih[(size_t)jm * 128 + k]);
    return;
  }
  t -= 49152;
  if (t < 384) {
    int jm = t < 128 ? t : t + 128;
    lbias[t] = lbih[jm] + lbhh[jm];
  }
}

// Bp[j,k] = sum_c W[k,c] * gwih[j,c]  (fold of conv-W into GRU input weight)
__global__ __launch_bounds__(256) void prepbp_k(const float* __restrict__ W,
                                                const float* __restrict__ gwih,
                                                unsigned short* __restrict__ Bpb) {
  int t = blockIdx.x * 256 + threadIdx.x;
  if (t >= 49152) return;
  int j = t >> 7, k = t & 127;
  const float4* wr = reinterpret_cast<const float4*>(W + (size_t)k * 128);
  const float4* gr = reinterpret_cast<const float4*>(gwih + (size_t)j * 128);
  float acc = 0.f;
#pragma unroll
  for (int c = 0; c < 32; ++c) {
    float4 a = wr[c], b = gr[c];
    acc += a.x * b.x + a.y * b.y + a.z * b.z + a.w * b.w;
  }
  Bpb[t] = f2bf(acc);
}

// ---------------- gather (fp8 in, bf16 out) — r1 structure, single dispatch ----------------
// Bound by random-transaction rate (~40G/s): 1 transaction/edge is the floor
// (~89us). Split dispatches cost +10us (r12) — keep it single.
__device__ __forceinline__ void accf8(f32x2* acc, uint4 v) {
  acc[0] += __builtin_amdgcn_cvt_pk_f32_fp8((int)v.x, false);
  acc[1] += __builtin_amdgcn_cvt_pk_f32_fp8((int)v.x, true);
  acc[2] += __builtin_amdgcn_cvt_pk_f32_fp8((int)v.y, false);
  acc[3] += __builtin_amdgcn_cvt_pk_f32_fp8((int)v.y, true);
  acc[4] += __builtin_amdgcn_cvt_pk_f32_fp8((int)v.z, false);
  acc[5] += __builtin_amdgcn_cvt_pk_f32_fp8((int)v.z, true);
  acc[6] += __builtin_amdgcn_cvt_pk_f32_fp8((int)v.w, false);
  acc[7] += __builtin_amdgcn_cvt_pk_f32_fp8((int)v.w, true);
}

__global__ __launch_bounds__(256) void gather_f8_k(const int* __restrict__ csr,
                                                   const int* __restrict__ rowstart,
                                                   const unsigned* __restrict__ x8,
                                                   unsigned short* __restrict__ xaggb, int N) {
  int w = (int)(((long long)blockIdx.x * 256 + threadIdx.x) >> 6);
  if (w >= N) return;
  const int lane = threadIdx.x & 63;
  const int sub = lane >> 3, li = lane & 7;
  const int beg = rowstart[w], end = rowstart[w + 1];
  const uint4* x4 = reinterpret_cast<const uint4*>(x8);  // row = 8 uint4 (128B)

  f32x2 acc[8];
#pragma unroll
  for (int i = 0; i < 8; ++i) acc[i] = (f32x2)0.f;

  int j = beg;
  for (; j + 16 <= end; j += 16) {
    int s0 = __builtin_nontemporal_load(&csr[j + sub]);
    int s1 = __builtin_nontemporal_load(&csr[j + 8 + sub]);
    uint4 v0 = x4[(size_t)s0 * 8 + li];
    uint4 v1 = x4[(size_t)s1 * 8 + li];
    accf8(acc, v0);
    accf8(acc, v1);
  }
  for (; j + 8 <= end; j += 8) {
    int s0 = __builtin_nontemporal_load(&csr[j + sub]);
    uint4 v0 = x4[(size_t)s0 * 8 + li];
    accf8(acc, v0);
  }
  int rem = end - j;  // 0..7
  if (sub < rem) {
    int s0 = csr[j + sub];
    uint4 v0 = x4[(size_t)s0 * 8 + li];
    accf8(acc, v0);
  }

  float a16[16];
#pragma unroll
  for (int i = 0; i < 8; ++i) { a16[2 * i] = acc[i].x; a16[2 * i + 1] = acc[i].y; }
#pragma unroll
  for (int i = 0; i < 16; ++i) {
    a16[i] += __shfl_xor(a16[i], 8, 64);
    a16[i] += __shfl_xor(a16[i], 16, 64);
    a16[i] += __shfl_xor(a16[i], 32, 64);
  }

  if (lane < 8) {
    float scale = 1.0f / fmaxf((float)(end - beg), 1.0f);
    u32x4 o1, o2;
    o1.x = (unsigned)f2bf(a16[0] * scale) | ((unsigned)f2bf(a16[1] * scale) << 16);
    o1.y = (unsigned)f2bf(a16[2] * scale) | ((unsigned)f2bf(a16[3] * scale) << 16);
    o1.z = (unsigned)f2bf(a16[4] * scale) | ((unsigned)f2bf(a16[5] * scale) << 16);
    o1.w = (unsigned)f2bf(a16[6] * scale) | ((unsigned)f2bf(a16[7] * scale) << 16);
    o2.x = (unsigned)f2bf(a16[8] * scale) | ((unsigned)f2bf(a16[9] * scale) << 16);
    o2.y = (unsigned)f2bf(a16[10] * scale) | ((unsigned)f2bf(a16[11] * scale) << 16);
    o2.z = (unsigned)f2bf(a16[12] * scale) | ((unsigned)f2bf(a16[13] * scale) << 16);
    o2.w = (unsigned)f2bf(a16[14] * scale) | ((unsigned)f2bf(a16[15] * scale) << 16);
    u32x4* dst = reinterpret_cast<u32x4*>(xaggb + (size_t)w * HD) + li * 2;
    dst[0] = o1;   // cached stores: downstream gru reads can hit cache
    dst[1] = o2;
  }
}

// ---------------- fused GRU: r10 structure (two-stage staging, XCD swizzle) ----------------
__global__ __launch_bounds__(256) void gru_fused_k(
    const unsigned short* __restrict__ xaggb, const unsigned short* __restrict__ xb,
    const unsigned short* __restrict__ Bpb, const unsigned short* __restrict__ gwhhb,
    const float* __restrict__ gbih, const float* __restrict__ gbhh,
    unsigned short* __restrict__ hconv, int nrows, int nt) {
  __shared__ unsigned short Bsm[3][32][136];
  const int id = blockIdx.x;
  const int rest = id >> 3;
  const int cg = rest & 3;
  const int t = ((rest >> 2) << 3) | (id & 7);
  if (t >= nt) return;  // uniform over block (before any barrier)
  const int tid = threadIdx.x;
  const int w = tid >> 6, lane = tid & 63;
  const int q = lane >> 4, r = lane & 15;
  const int row0 = t * 64;
  const int c0 = cg * 32;

  // A fragments (issued early; global latency hides under staging)
  int arow = row0 + (w << 4) + r;
  int ar = arow < nrows ? arow : nrows - 1;
  const unsigned short* Aa = xaggb + (size_t)ar * HD + q * 8;
  const unsigned short* Ax = xb + (size_t)ar * HD + q * 8;
  short8 a1[4], a2[4];
#pragma unroll
  for (int ks = 0; ks < 4; ++ks) {
    a1[ks] = *reinterpret_cast<const short8*>(Aa + ks * 32);
    a2[ks] = *reinterpret_cast<const short8*>(Ax + ks * 32);
  }

  f32x4 acc[6][2];
#pragma unroll
  for (int p = 0; p < 6; ++p)
#pragma unroll
    for (int cb = 0; cb < 2; ++cb) acc[p][cb] = (f32x4)0.f;

  // ---- stage set 0: Bp planes (ir, iz, in) ----
#pragma unroll
  for (int it = 0; it < 6; ++it) {
    int idx = it * 256 + tid;
    int p = idx >> 9, rem = idx & 511;
    int col = rem >> 4, kq = rem & 15;
    uint4 v = *reinterpret_cast<const uint4*>(
        Bpb + ((size_t)(p * 128 + c0 + col)) * HD + kq * 8);
    *reinterpret_cast<uint4*>(&Bsm[p][col][kq * 8]) = v;
  }
  __syncthreads();
#pragma unroll
  for (int ks = 0; ks < 4; ++ks)
#pragma unroll
    for (int p = 0; p < 3; ++p)
#pragma unroll
      for (int cb = 0; cb < 2; ++cb) {
        short8 bf = *reinterpret_cast<const short8*>(&Bsm[p][cb * 16 + r][ks * 32 + q * 8]);
        acc[p][cb] = __builtin_amdgcn_mfma_f32_16x16x32_bf16(a1[ks], bf, acc[p][cb], 0, 0, 0);
      }
  __syncthreads();

  // ---- stage set 1: gwhh planes (hr, hz, hn) ----
#pragma unroll
  for (int it = 0; it < 6; ++it) {
    int idx = it * 256 + tid;
    int p = idx >> 9, rem = idx & 511;
    int col = rem >> 4, kq = rem & 15;
    uint4 v = *reinterpret_cast<const uint4*>(
        gwhhb + ((size_t)(p * 128 + c0 + col)) * HD + kq * 8);
    *reinterpret_cast<uint4*>(&Bsm[p][col][kq * 8]) = v;
  }
  __syncthreads();
#pragma unroll
  for (int ks = 0; ks < 4; ++ks)
#pragma unroll
    for (int p = 0; p < 3; ++p)
#pragma unroll
      for (int cb = 0; cb < 2; ++cb) {
        short8 bf = *reinterpret_cast<const short8*>(&Bsm[p][cb * 16 + r][ks * 32 + q * 8]);
        acc[3 + p][cb] = __builtin_amdgcn_mfma_f32_16x16x32_bf16(a2[ks], bf, acc[3 + p][cb], 0, 0, 0);
      }

  // ---- epilogue ----
#pragma unroll
  for (int cb = 0; cb < 2; ++cb) {
    int col = c0 + cb * 16 + r;
    float bir = gbih[col], biz = gbih[col + 128], bin = gbih[col + 256];
    float bhr = gbhh[col], bhz = gbhh[col + 128], bhn = gbhh[col + 256];
#pragma unroll
    for (int reg = 0; reg < 4; ++reg) {
      int row = row0 + (w << 4) + q * 4 + reg;
      if (row < nrows) {
        float ir = acc[0][cb][reg] + bir, iz = acc[1][cb][reg] + biz;
        float inn = acc[2][cb][reg] + bin;
        float hr = acc[3][cb][reg] + bhr, hz = acc[4][cb][reg] + bhz;
        float hn = acc[5][cb][reg] + bhn;
        float rr = sigf(ir + hr), zz = sigf(iz + hz);
        float nn = tanhf_fast(inn + rr * hn);
        float xv = bf2f(xb[(size_t)row * HD + col]);
        hconv[(size_t)row * HD + col] = f2bf((1.f - zz) * nn + zz * xv);
      }
    }
  }
}

// ---------------- fused LSTM: 32-col blocks, XCD-swizzled 1D grid (r10) ----------------
__global__ __launch_bounds__(256) void lstm_fused_k(
    const unsigned short* __restrict__ hconv, const unsigned short* __restrict__ lwb,
    const float* __restrict__ lbias, float* __restrict__ out, int nrows, int nt) {
  __shared__ unsigned short Bsm[3][32][136];
  const int id = blockIdx.x;
  const int rest = id >> 3;
  const int cg = rest & 3;
  const int t = ((rest >> 2) << 3) | (id & 7);
  if (t >= nt) return;
  const int tid = threadIdx.x;
  const int w = tid >> 6, lane = tid & 63;
  const int q = lane >> 4, r = lane & 15;
  const int row0 = t * 64;
  const int c0 = cg * 32;

  int arow = row0 + (w << 4) + r;
  int ar = arow < nrows ? arow : nrows - 1;
  const unsigned short* Ap = hconv + (size_t)ar * HD + q * 8;
  short8 hp[4];
#pragma unroll
  for (int ks = 0; ks < 4; ++ks)
    hp[ks] = *reinterpret_cast<const short8*>(Ap + ks * 32);

#pragma unroll
  for (int it = 0; it < 6; ++it) {
    int idx = it * 256 + tid;
    int p = idx >> 9, rem = idx & 511;
    int col = rem >> 4, kq = rem & 15;
    uint4 v = *reinterpret_cast<const uint4*>(
        lwb + ((size_t)(p * 128 + c0 + col)) * HD + kq * 8);
    *reinterpret_cast<uint4*>(&Bsm[p][col][kq * 8]) = v;
  }
  __syncthreads();

  f32x4 acc[3][2];
#pragma unroll
  for (int p = 0; p < 3; ++p)
#pragma unroll
    for (int cb = 0; cb < 2; ++cb) acc[p][cb] = (f32x4)0.f;

#pragma unroll
  for (int ks = 0; ks < 4; ++ks)
#pragma unroll
    for (int p = 0; p < 3; ++p)
#pragma unroll
      for (int cb = 0; cb < 2; ++cb) {
        short8 bf = *reinterpret_cast<const short8*>(&Bsm[p][cb * 16 + r][ks * 32 + q * 8]);
        acc[p][cb] = __builtin_amdgcn_mfma_f32_16x16x32_bf16(hp[ks], bf, acc[p][cb], 0, 0, 0);
      }

#pragma unroll
  for (int cb = 0; cb < 2; ++cb) {
    int col = c0 + cb * 16 + r;
    float bi = lbias[col], bg = lbias[col + 128], bo = lbias[col + 256];
#pragma unroll
    for (int reg = 0; reg < 4; ++reg) {
      int row = row0 + (w << 4) + q * 4 + reg;
      if (row < nrows) {
        float ig = acc[0][cb][reg] + bi;
        float gg = acc[1][cb][reg] + bg;
        float og = acc[2][cb][reg] + bo;
        float cc = sigf(ig) * tanhf_fast(gg);
        out[(size_t)row * HD + col] = fmaxf(sigf(og) * tanhf_fast(cc), 0.f);
      }
    }
  }
}

// ---------------- host ----------------

extern "C" void kernel_launch(void* const* d_in, const int* in_sizes, int n_in,
                              void* d_out, int out_size, void* d_ws, size_t ws_size,
                              hipStream_t stream) {
  const float* x = (const float*)d_in[0];
  const int* ei = (const int*)d_in[1];
  const float* W = (const float*)d_in[2];
  const float* gw_ih = (const float*)d_in[3];
  const float* gw_hh = (const float*)d_in[4];
  const float* gb_ih = (const float*)d_in[5];
  const float* gb_hh = (const float*)d_in[6];
  const float* lw_ih = (const float*)d_in[7];
  const float* lb_ih = (const float*)d_in[9];
  const float* lb_hh = (const float*)d_in[10];
  float* out = (float*)d_out;

  const int N = in_sizes[0] / HD;
  const int E = in_sizes[1] / 2;
  const size_t nH = (size_t)N * HD;

  int shift = 9;
  while (((N + (1 << shift) - 1) >> shift) > 256) ++shift;
  const int NB = (N + (1 << shift) - 1) >> shift;
  const int sbits = 32 - shift;

  const size_t N4p = (size_t)((N + 1 + 7) & ~7);  // rowstart: N+1
  const size_t E4 = (size_t)((E + 3) & ~3);
  const size_t BC = (size_t)NB * PB + 8;
  const int sc_total = NB * PB;
  const int sc_nblk = (sc_total + SCB - 1) / SCB;

  // ws layout: [rowstart][bcnt][bsums][csr][ebuf|xb][hconv|x8][Bpb][gwhhb][lwb][lbias]
  char* p = (char*)d_ws;
  int* rowstart = (int*)p;  p += 4 * N4p;
  int* bcnt = (int*)p;      p += 4 * BC;
  int* bsums = (int*)p;     p += 4 * 64;
  int* csr = (int*)p;       p += 4 * E4;
  size_t sz_eb = 4 * E4, sz_xb = 2 * nH;
  unsigned* ebuf = (unsigned*)p;            // dead after bfill2_k
  unsigned short* xb = (unsigned short*)p;  // written by convprep_k after
  p += (sz_eb > sz_xb ? sz_eb : sz_xb);
  unsigned short* hconv = (unsigned short*)p;  p += 2 * nH;
  unsigned short* Bpb = (unsigned short*)p;    p += 2 * 49152;
  unsigned short* gwhhb = (unsigned short*)p;  p += 2 * 49152;
  unsigned short* lwb = (unsigned short*)p;    p += 2 * 49152;
  float* lbias = (float*)p;                    p += 4 * 384;

  // fp8 x table aliases hconv region (hconv first written by gru_fused_k,
  // which runs after gather_f8_k has fully consumed x8). nH bytes <= 2*nH.
  unsigned* x8 = (unsigned*)hconv;

  unsigned short* xaggb = (unsigned short*)d_out;  // consumed before out written

  dim3 blk(256);
  unsigned rb = (unsigned)((N + 63) / 64);
  unsigned rb8 = (rb + 7) & ~7u;  // padded so the swizzle decode covers all tiles

  // CSR build (bucketed) — 5 dispatches
  bcount_k<<<PB, blk, 0, stream>>>(ei, bcnt, E, N, shift, NB);
  scan1_k<<<sc_nblk, blk, 0, stream>>>(bcnt, bsums, sc_total);
  scan3_k<<<sc_nblk, blk, 0, stream>>>(bcnt, bsums, sc_total, sc_nblk);
  bpart_k<<<PB, blk, 0, stream>>>(ei, bcnt, ebuf, E, N, shift, NB, sbits);
  bfill2_k<<<NB, blk, 0, stream>>>(ebuf, bcnt, rowstart, csr, N, shift, NB, sbits);

  // conversions (convx+prepw merged) + weight fold — 2 dispatches
  int n4 = (int)(nH / 4);
  int cp_total = n4 + 49152 + 49152 + 384;
  convprep_k<<<(unsigned)((cp_total + 255) / 256), blk, 0, stream>>>(
      x, xb, x8, gw_hh, lw_ih, lb_ih, lb_hh, gwhhb, lwb, lbias, n4);
  prepbp_k<<<192, blk, 0, stream>>>(W, gw_ih, Bpb);

  // aggregation (fp8 source rows, 128B/edge) — single dispatch
  long long gthreads = (long long)N * 64;
  gather_f8_k<<<(unsigned)((gthreads + 255) / 256), blk, 0, stream>>>(
      csr, rowstart, x8, xaggb, N);

  // hconv = GRU(xagg, x) with W folded into the input-gate weight
  gru_fused_k<<<4 * rb8, blk, 0, stream>>>(
      xaggb, xb, Bpb, gwhhb, gb_ih, gb_hh, hconv, N, (int)rb);

  // out = LSTM(hconv)
  lstm_fused_k<<<4 * rb8, blk, 0, stream>>>(hconv, lwb, lbias, out, N, (int)rb);
}